// Round 1
// baseline (348.787 us; speedup 1.0000x reference)
//
#include <hip/hip_runtime.h>
#include <cstddef>

#define SEQ  1024
#define BATCH 16
#define CIN  512
#define COUT 512
#define MROWS (SEQ*BATCH)   // 16384

__device__ float g_w2[3*CIN*COUT];   // w2[k][i][o]
__device__ float g_xo[MROWS];        // x_output[s][b]
__device__ float g_xoT[BATCH*SEQ];   // xoT[b][t]
__device__ float g_minv;

__device__ __forceinline__ float ht_f(float x){
    float t = fminf(fmaxf(x*10.f, -1.f), 1.f);
    return fmaf(t, 0.5f, 0.5f);
}

// conv_w[o][i][k] -> g_w2[k][i][o]
__global__ __launch_bounds__(256) void prep_w(const float* __restrict__ w){
    int idx = blockIdx.x*256 + threadIdx.x;       // 3*512*512 = 786432 exact
    int o = idx & 511;
    int i = (idx >> 9) & 511;
    int k = idx >> 18;
    g_w2[idx] = w[(o*CIN + i)*3 + k];
}

// f32 GEMM: A[r][kk]=x[(s+kw-2)*16+b][i] (kk=kw*512+i), B[kk][o]=g_w2, fused epilogue
__global__ __launch_bounds__(512) void conv_gemm(
        const float* __restrict__ x, const float* __restrict__ cb,
        const float* __restrict__ lw, const float* __restrict__ lb){
    __shared__ __align__(16) float Asm[16][64];    // [kk][row]
    __shared__ __align__(16) float Bsm[16][512];   // [kk][col]
    const int tid = threadIdx.x;
    const int r0  = blockIdx.x * 64;
    const int wv  = tid >> 6;
    const int ln  = tid & 63;
    float acc[8][8];
#pragma unroll
    for (int i=0;i<8;i++)
#pragma unroll
        for (int j=0;j<8;j++) acc[i][j]=0.f;

    const int a_row = tid >> 3;
    const int a_kk  = (tid & 7) * 2;
    const int b_kk  = tid >> 5;
    const int b_o0  = (tid & 31) * 16;
    const int rA = r0 + a_row;
    const int sA = rA >> 4;

#pragma unroll 1
    for (int kb=0; kb<96; ++kb){
        const int kkg = kb*16;
        const int kw  = kkg >> 9;
        const int i0  = kkg & 511;
        float2 av = make_float2(0.f, 0.f);
        if (sA + kw >= 2){
            const float* px = x + (size_t)(rA + (kw-2)*BATCH)*CIN + (i0 + a_kk);
            av = *(const float2*)px;
        }
        const float* pw = g_w2 + (size_t)(kkg + b_kk)*COUT + b_o0;
        float4 q0 = *(const float4*)(pw+0);
        float4 q1 = *(const float4*)(pw+4);
        float4 q2 = *(const float4*)(pw+8);
        float4 q3 = *(const float4*)(pw+12);
        __syncthreads();
        Asm[a_kk  ][a_row] = av.x;
        Asm[a_kk+1][a_row] = av.y;
        *(float4*)&Bsm[b_kk][b_o0+ 0] = q0;
        *(float4*)&Bsm[b_kk][b_o0+ 4] = q1;
        *(float4*)&Bsm[b_kk][b_o0+ 8] = q2;
        *(float4*)&Bsm[b_kk][b_o0+12] = q3;
        __syncthreads();
#pragma unroll
        for (int kk=0; kk<16; ++kk){
            float4 a0 = *(const float4*)&Asm[kk][wv*8+0];
            float4 a1 = *(const float4*)&Asm[kk][wv*8+4];
            float4 b0 = *(const float4*)&Bsm[kk][ln*4];
            float4 b1 = *(const float4*)&Bsm[kk][ln*4+256];
            float a[8]  = {a0.x,a0.y,a0.z,a0.w,a1.x,a1.y,a1.z,a1.w};
            float bb[8] = {b0.x,b0.y,b0.z,b0.w,b1.x,b1.y,b1.z,b1.w};
#pragma unroll
            for (int i=0;i<8;i++)
#pragma unroll
                for (int j=0;j<8;j++)
                    acc[i][j] = fmaf(a[i], bb[j], acc[i][j]);
        }
    }
    // epilogue: xo[r] = sum_o relu(acc+cb[o])*lw[o] + lb
    const int clo = ln*4, chi = ln*4+256;
    float cbv[8] = {cb[clo],cb[clo+1],cb[clo+2],cb[clo+3],
                    cb[chi],cb[chi+1],cb[chi+2],cb[chi+3]};
    float lwv[8] = {lw[clo],lw[clo+1],lw[clo+2],lw[clo+3],
                    lw[chi],lw[chi+1],lw[chi+2],lw[chi+3]};
    const float lbv = lb[0];
#pragma unroll
    for (int i=0;i<8;i++){
        float s = 0.f;
#pragma unroll
        for (int j=0;j<8;j++){
            float y = fmaxf(acc[i][j] + cbv[j], 0.f);
            s = fmaf(y, lwv[j], s);
        }
#pragma unroll
        for (int d=32; d; d>>=1) s += __shfl_down(s, d);
        if (ln==0) g_xo[r0 + wv*8 + i] = s + lbv;
    }
}

// single block: min, sum-sq, transpose xo -> xoT; write seq_len & reg_len outputs
__global__ __launch_bounds__(1024) void reduce_transpose(float* __restrict__ out, int R){
    const int tid = threadIdx.x;
    float mn = 3.4e38f, ss = 0.f;
#pragma unroll
    for (int k=0;k<16;k++){
        int flat = k*1024 + tid;
        float v = g_xo[flat];
        mn = fminf(mn, v);
        ss = fmaf(v, v, ss);
        g_xoT[(flat & 15)*SEQ + (flat >> 4)] = v;
    }
    __shared__ float smn[16], sss[16];
#pragma unroll
    for (int d=32; d; d>>=1){ mn = fminf(mn, __shfl_xor(mn, d)); ss += __shfl_xor(ss, d); }
    int w = tid >> 6, l = tid & 63;
    if (l==0){ smn[w]=mn; sss[w]=ss; }
    __syncthreads();
    if (tid==0){
        float m = smn[0], s2 = sss[0];
        for (int i=1;i<16;i++){ m = fminf(m, smn[i]); s2 += sss[i]; }
        g_minv = m;
        out[(size_t)R*MROWS]     = (float)R;          // seq_len_data
        out[(size_t)R*MROWS + 1] = s2 / (float)MROWS; // reg_len
    }
}

// one block per s; wave w = batch b; lane owns 16 consecutive t; prefix-product scan
__global__ __launch_bounds__(1024) void attn_kernel(float* __restrict__ out, int R){
    const int s   = blockIdx.x;
    const int tid = threadIdx.x;
    const int w   = tid >> 6;      // b
    const int l   = tid & 63;
    __shared__ __align__(16) float stage[BATCH][SEQ+1];
    const float minv = g_minv;
    const float* xb = g_xoT + (size_t)w * SEQ;
    const float xo_s = xb[s];
    const int t0 = l << 4;
    float val[16];
    {
        float4* vv = (float4*)val;
        const float4* src = (const float4*)(xb + t0);
        vv[0]=src[0]; vv[1]=src[1]; vv[2]=src[2]; vv[3]=src[3];
    }
    const float prev = (t0 == 0) ? 0.f : xb[t0-1];
    float f[16];
#pragma unroll
    for (int j=0;j<16;j++){
        int t = t0 + j;
        float xsd = (j==0) ? prev : val[j-1];
        float c2  = ht_f(xsd - val[j]);
        float a   = ht_f(xsd - xo_s);
        float fac = 1.f - a*c2;
        f[j] = (t <= s+1) ? 1.f : fac;
    }
    // local inclusive products
    float p = 1.f;
#pragma unroll
    for (int j=0;j<16;j++){ p *= f[j]; f[j] = p; }
    // wave-wide inclusive scan of chunk products -> exclusive prefix
    float sc = p;
#pragma unroll
    for (int d=1; d<64; d<<=1){ float v = __shfl_up(sc, d); if (l >= d) sc *= v; }
    float ex = __shfl_up(sc, 1);
    if (l == 0) ex = 1.f;
    // scores + row sum
    float ssum = 0.f;
#pragma unroll
    for (int j=0;j<16;j++){
        int t = t0 + j;
        float scv = (t > s) ? ex * f[j] * (val[j] - minv + 10.f) : 0.f;
        f[j] = scv;
        ssum += scv;
    }
#pragma unroll
    for (int d=32; d; d>>=1) ssum += __shfl_xor(ssum, d);
    float inv = (ssum > 0.f) ? 1.f/ssum : 0.f;
#pragma unroll
    for (int j=0;j<16;j++) stage[w][t0+j] = f[j]*inv;
    __syncthreads();
    // coalesced float4 writes: flat = t*16 + b
    float* op = out + (size_t)s * MROWS;
#pragma unroll
    for (int k=0;k<4;k++){
        int flat = (k*1024 + tid)*4;
        float4 q;
        q.x = stage[(flat  )&15][(flat  )>>4];
        q.y = stage[(flat+1)&15][(flat+1)>>4];
        q.z = stage[(flat+2)&15][(flat+2)>>4];
        q.w = stage[(flat+3)&15][(flat+3)>>4];
        *(float4*)(op + flat) = q;
    }
}

extern "C" void kernel_launch(void* const* d_in, const int* in_sizes, int n_in,
                              void* d_out, int out_size, void* d_ws, size_t ws_size,
                              hipStream_t stream){
    const float* x  = (const float*)d_in[0];
    const float* w  = (const float*)d_in[1];
    const float* cb = (const float*)d_in[2];
    const float* lw = (const float*)d_in[3];
    const float* lb = (const float*)d_in[4];
    float* out = (float*)d_out;
    const int R = (out_size - 2) / MROWS;   // expected 1023

    hipLaunchKernelGGL(prep_w,           dim3(3072), dim3(256),  0, stream, w);
    hipLaunchKernelGGL(conv_gemm,        dim3(256),  dim3(512),  0, stream, x, cb, lw, lb);
    hipLaunchKernelGGL(reduce_transpose, dim3(1),    dim3(1024), 0, stream, out, R);
    hipLaunchKernelGGL(attn_kernel,      dim3(R),    dim3(1024), 0, stream, out, R);
}